// Round 1
// baseline (401.279 us; speedup 1.0000x reference)
//
#include <hip/hip_runtime.h>

#define EMBED   768
#define EMBED4  192
#define POOL    60
#define BATCH   128
#define SEQ     512
#define TOPK    5
#define LEN     5
#define OUTROWS 537   // TOPK*LEN + SEQ = 25 + 512

// ---- output layout (float offsets, concatenated in reference return order) ----
#define SZ_PE   (128L*537L*768L)          // 52,789,248
#define OFF_RS  (SZ_PE)                   // reduce_sim scalar
#define OFF_IDX (OFF_RS + 1)              // 128*5 = 640
#define OFF_SIM (OFF_IDX + 640)           // 128*60 = 7680
#define OFF_SK  (OFF_SIM + 7680)          // 128*5*768 = 491,520

// ---- workspace layout (float offsets) ----
#define WS_PARTIAL 0                      // 128*4*768 = 393,216
#define WS_MEAN    393216                 // 128*768   =  98,304
#define WS_KEYBALL 491520                 // 60*768    =  46,080
#define WS_KEYY2   537600                 // 60
#define WS_IDX     537664                 // 640 ints

#define MAX_NORM_F 0.996f                 // 1.0 - 4e-3

__device__ __forceinline__ float block_reduce_256(float v, float* red) {
    int tid = threadIdx.x;
    #pragma unroll
    for (int m = 32; m >= 1; m >>= 1) v += __shfl_xor(v, m, 64);
    if ((tid & 63) == 0) red[tid >> 6] = v;
    __syncthreads();
    float total = red[0] + red[1] + red[2] + red[3];
    __syncthreads();   // guard before red[] reuse
    return total;
}

// Fused: stream x_embed -> output rows [25..536] while accumulating per-batch partial sums.
// grid (4 slices, 128 batches), block 192 (one float4 column per thread)
__global__ __launch_bounds__(192) void mean_partial_copy(
        const float* __restrict__ x, float* __restrict__ out, float* __restrict__ partial) {
    const int slice = blockIdx.x, b = blockIdx.y, tid = threadIdx.x;
    const float4* __restrict__ x4 = (const float4*)x;
    float4* __restrict__ out4 = (float4*)out;
    float4* __restrict__ p4 = (float4*)partial;

    float4 acc = make_float4(0.f, 0.f, 0.f, 0.f);
    const long srow = (long)b * SEQ + slice * 128;
    const long obase = ((long)b * OUTROWS + 25 + slice * 128) * EMBED4 + tid;
    const long ibase = srow * EMBED4 + tid;
    for (int s = 0; s < 128; ++s) {
        float4 v = x4[ibase + (long)s * EMBED4];
        acc.x += v.x; acc.y += v.y; acc.z += v.z; acc.w += v.w;
        out4[obase + (long)s * EMBED4] = v;
    }
    p4[(long)(b * 4 + slice) * EMBED4 + tid] = acc;
}

// grid 128, block 192
__global__ __launch_bounds__(192) void finalize_mean(
        const float* __restrict__ partial, float* __restrict__ mean) {
    const int b = blockIdx.x, tid = threadIdx.x;
    const float4* __restrict__ p4 = (const float4*)partial;
    float4* __restrict__ m4 = (float4*)mean;
    float4 a = p4[(b * 4 + 0) * EMBED4 + tid];
    float4 c = p4[(b * 4 + 1) * EMBED4 + tid];
    float4 d = p4[(b * 4 + 2) * EMBED4 + tid];
    float4 e = p4[(b * 4 + 3) * EMBED4 + tid];
    const float inv = 1.0f / 512.0f;
    float4 r;
    r.x = (a.x + c.x + d.x + e.x) * inv;
    r.y = (a.y + c.y + d.y + e.y) * inv;
    r.z = (a.z + c.z + d.z + e.z) * inv;
    r.w = (a.w + c.w + d.w + e.w) * inv;
    m4[b * EMBED4 + tid] = r;
}

// map_to_ball(prompt_key) -> keyball, keyy2.  grid 60, block 256 (3 elems/thread)
__global__ __launch_bounds__(256) void keyball_kernel(
        const float* __restrict__ pkey, float* __restrict__ keyball, float* __restrict__ keyy2) {
    __shared__ float red[4];
    const int p = blockIdx.x, tid = threadIdx.x;
    float v[3];
    float ss = 0.f;
    #pragma unroll
    for (int j = 0; j < 3; ++j) { v[j] = pkey[p * EMBED + tid + 256 * j]; ss += v[j] * v[j]; }
    ss = block_reduce_256(ss, red);
    const float scale1 = rsqrtf(fmaxf(ss, 1e-12f)) * 0.1f;   // l2_normalize * MAP_SCALE
    float su = 0.f;
    #pragma unroll
    for (int j = 0; j < 3; ++j) { v[j] *= scale1; su += v[j] * v[j]; }
    su = block_reduce_256(su, red);
    const float n = sqrtf(fmaxf(su, 1e-15f));
    const float f = tanhf(n) / n;                             // expmap0
    float sb = 0.f;
    #pragma unroll
    for (int j = 0; j < 3; ++j) { v[j] *= f; sb += v[j] * v[j]; }
    sb = block_reduce_256(sb, red);
    const float n2 = sqrtf(fmaxf(sb, 1e-15f));
    const float g = (n2 > MAX_NORM_F) ? (MAX_NORM_F / n2) : 1.0f;  // proju0
    #pragma unroll
    for (int j = 0; j < 3; ++j) keyball[p * EMBED + tid + 256 * j] = v[j] * g;
    if (tid == 0) keyy2[p] = sb * g * g;
}

// Per-batch: q_ball, distances, similarity, top-5, idx, reduce_sim, selected_key.
// grid 128, block 256
__global__ __launch_bounds__(256) void topk_kernel(
        const float* __restrict__ mean, const float* __restrict__ keyball,
        const float* __restrict__ keyy2, float* __restrict__ out, int* __restrict__ idxws) {
    __shared__ float red[4];
    __shared__ float q[EMBED];
    __shared__ float xy[POOL];
    __shared__ float dist[POOL];
    __shared__ int sel_sh[TOPK];
    const int b = blockIdx.x, tid = threadIdx.x;

    // ---- q_ball = map_to_ball(x_mean[b]) ----
    float v[3];
    float ss = 0.f;
    #pragma unroll
    for (int j = 0; j < 3; ++j) { v[j] = mean[b * EMBED + tid + 256 * j]; ss += v[j] * v[j]; }
    ss = block_reduce_256(ss, red);
    const float scale1 = rsqrtf(fmaxf(ss, 1e-12f)) * 0.1f;
    float su = 0.f;
    #pragma unroll
    for (int j = 0; j < 3; ++j) { v[j] *= scale1; su += v[j] * v[j]; }
    su = block_reduce_256(su, red);
    const float n = sqrtf(fmaxf(su, 1e-15f));
    const float f = tanhf(n) / n;
    float sb = 0.f;
    #pragma unroll
    for (int j = 0; j < 3; ++j) { v[j] *= f; sb += v[j] * v[j]; }
    sb = block_reduce_256(sb, red);
    const float n2 = sqrtf(fmaxf(sb, 1e-15f));
    const float g = (n2 > MAX_NORM_F) ? (MAX_NORM_F / n2) : 1.0f;
    const float x2 = sb * g * g;
    #pragma unroll
    for (int j = 0; j < 3; ++j) q[tid + 256 * j] = v[j] * g;
    __syncthreads();

    // ---- xy[p] = <q, key_ball[p]> : each wave handles 15 keys ----
    const int wave = tid >> 6, lane = tid & 63;
    for (int p = wave; p < POOL; p += 4) {
        const float* __restrict__ kb = keyball + p * EMBED;
        float acc = 0.f;
        #pragma unroll
        for (int d = 0; d < EMBED; d += 64) acc += q[d + lane] * kb[d + lane];
        #pragma unroll
        for (int m = 32; m >= 1; m >>= 1) acc += __shfl_xor(acc, m, 64);
        if (lane == 0) xy[p] = acc;
    }
    __syncthreads();

    // ---- distances (scalar-only mobius math) ----
    if (tid < POOL) {
        const float s = xy[tid];
        const float y2 = keyy2[tid];
        const float A = 1.0f - 2.0f * s + y2;       // coeff on -x in num
        const float B = 1.0f - x2;                  // coeff on  y in num
        const float num2 = A * A * x2 + B * B * y2 - 2.0f * A * B * s;
        const float den = fmaxf(1.0f - 2.0f * s + x2 * y2, 1e-15f);
        float nn = sqrtf(fmaxf(num2 / (den * den), 1e-15f));
        nn = fminf(fmaxf(nn, 0.0f), 1.0f - 1e-7f);
        const float dd = logf((1.0f + nn) / (1.0f - nn));   // 2*artanh(nn)
        dist[tid] = dd;
        out[OFF_SIM + (long)b * POOL + tid] = -dd;
    }
    __syncthreads();

    // ---- top-5 (largest similarity = smallest dist; ties -> lowest index), sort, reduce_sim ----
    if (tid == 0) {
        int sel[TOPK];
        unsigned long long mask = 0ULL;
        for (int k = 0; k < TOPK; ++k) {
            int best = 0; float bd = 1e30f;
            for (int p = 0; p < POOL; ++p) {
                if (mask & (1ULL << p)) continue;
                if (dist[p] < bd) { bd = dist[p]; best = p; }   // strict < keeps lowest index on tie
            }
            mask |= 1ULL << best;
            sel[k] = best;
        }
        #pragma unroll
        for (int i = 0; i < TOPK; ++i)
            for (int j2 = i + 1; j2 < TOPK; ++j2)
                if (sel[j2] < sel[i]) { int t = sel[i]; sel[i] = sel[j2]; sel[j2] = t; }
        float sum = 0.f;
        for (int k = 0; k < TOPK; ++k) {
            sum += dist[sel[k]];
            out[OFF_IDX + (long)b * TOPK + k] = (float)sel[k];
            idxws[b * TOPK + k] = sel[k];
            sel_sh[k] = sel[k];
        }
        atomicAdd(&out[OFF_RS], sum * (1.0f / 128.0f));
    }
    __syncthreads();

    // ---- selected_key[b] = key_ball[idx] ----
    for (int t = tid; t < TOPK * EMBED; t += 256) {
        const int k = t / EMBED, d = t - k * EMBED;
        out[OFF_SK + (long)b * TOPK * EMBED + t] = keyball[sel_sh[k] * EMBED + d];
    }
}

// Gather selected prompts into output rows [0..24].  grid (25,128), block 192
__global__ __launch_bounds__(192) void prompt_copy(
        const float* __restrict__ prompt, const int* __restrict__ idxws, float* __restrict__ out) {
    const int r = blockIdx.x, b = blockIdx.y, tid = threadIdx.x;
    const int k = r / LEN, l = r - k * LEN;
    const int pi = idxws[b * TOPK + k];
    const float4* __restrict__ p4 = (const float4*)prompt;
    float4* __restrict__ o4 = (float4*)out;
    o4[((long)b * OUTROWS + r) * EMBED4 + tid] = p4[((long)pi * LEN + l) * EMBED4 + tid];
}

extern "C" void kernel_launch(void* const* d_in, const int* in_sizes, int n_in,
                              void* d_out, int out_size, void* d_ws, size_t ws_size,
                              hipStream_t stream) {
    const float* x      = (const float*)d_in[0];   // [128,512,768]
    const float* prompt = (const float*)d_in[1];   // [60,5,768]
    const float* pkey   = (const float*)d_in[2];   // [60,768]
    float* out = (float*)d_out;
    float* ws  = (float*)d_ws;

    float* partial = ws + WS_PARTIAL;
    float* mean    = ws + WS_MEAN;
    float* keyball = ws + WS_KEYBALL;
    float* keyy2   = ws + WS_KEYY2;
    int*   idxws   = (int*)(ws + WS_IDX);

    // reduce_sim slot is accumulated via atomicAdd -> zero it every call
    hipMemsetAsync(out + OFF_RS, 0, sizeof(float), stream);

    hipLaunchKernelGGL(mean_partial_copy, dim3(4, 128), dim3(192), 0, stream, x, out, partial);
    hipLaunchKernelGGL(finalize_mean,     dim3(128),    dim3(192), 0, stream, partial, mean);
    hipLaunchKernelGGL(keyball_kernel,    dim3(60),     dim3(256), 0, stream, pkey, keyball, keyy2);
    hipLaunchKernelGGL(topk_kernel,       dim3(128),    dim3(256), 0, stream, mean, keyball, keyy2, out, idxws);
    hipLaunchKernelGGL(prompt_copy,       dim3(25, 128), dim3(192), 0, stream, prompt, idxws, out);
}

// Round 2
// 392.781 us; speedup vs baseline: 1.0216x; 1.0216x over previous
//
#include <hip/hip_runtime.h>

#define EMBED   768
#define EMBED4  192
#define POOL    60
#define BATCH   128
#define SEQ     512
#define TOPK    5
#define LEN     5
#define OUTROWS 537   // TOPK*LEN + SEQ = 25 + 512
#define NSLICE  16    // slices per batch in the streaming kernel

// ---- output layout (float offsets, concatenated in reference return order) ----
#define SZ_PE   (128L*537L*768L)          // 52,789,248
#define OFF_RS  (SZ_PE)                   // reduce_sim scalar
#define OFF_IDX (OFF_RS + 1)              // 128*5 = 640
#define OFF_SIM (OFF_IDX + 640)           // 128*60 = 7680
#define OFF_SK  (OFF_SIM + 7680)          // 128*5*768 = 491,520

// ---- workspace layout (float offsets) ----
#define WS_PARTIAL 0                      // 128*16*768 = 1,572,864
#define WS_KEYBALL 1572864                // 60*768     =    46,080
#define WS_KEYY2   1618944                // 60

#define MAX_NORM_F 0.996f                 // 1.0 - 4e-3

__device__ __forceinline__ float block_reduce_256(float v, float* red) {
    int tid = threadIdx.x;
    #pragma unroll
    for (int m = 32; m >= 1; m >>= 1) v += __shfl_xor(v, m, 64);
    if ((tid & 63) == 0) red[tid >> 6] = v;
    __syncthreads();
    float total = red[0] + red[1] + red[2] + red[3];
    __syncthreads();   // guard before red[] reuse
    return total;
}

// Fused: stream x_embed -> output rows [25..536] while accumulating per-batch partial sums.
// grid (NSLICE, 128 batches), block 192 (one float4 column per thread), 32 rows per block
__global__ __launch_bounds__(192) void mean_partial_copy(
        const float* __restrict__ x, float* __restrict__ out, float* __restrict__ partial) {
    const int slice = blockIdx.x, b = blockIdx.y, tid = threadIdx.x;
    const float4* __restrict__ x4 = (const float4*)x;
    float4* __restrict__ out4 = (float4*)out;
    float4* __restrict__ p4 = (float4*)partial;

    if (slice == 0 && b == 0 && tid == 0) out[OFF_RS] = 0.0f;  // zero reduce_sim (pre-topk, stream-ordered)

    float4 acc = make_float4(0.f, 0.f, 0.f, 0.f);
    const int rows = SEQ / NSLICE;  // 32
    const long ibase = ((long)b * SEQ + slice * rows) * EMBED4 + tid;
    const long obase = ((long)b * OUTROWS + 25 + slice * rows) * EMBED4 + tid;
    #pragma unroll 4
    for (int s = 0; s < rows; ++s) {
        float4 v = x4[ibase + (long)s * EMBED4];
        acc.x += v.x; acc.y += v.y; acc.z += v.z; acc.w += v.w;
        out4[obase + (long)s * EMBED4] = v;
    }
    p4[(long)(b * NSLICE + slice) * EMBED4 + tid] = acc;
}

// map_to_ball(prompt_key) -> keyball, keyy2.  grid 60, block 256 (3 elems/thread)
__global__ __launch_bounds__(256) void keyball_kernel(
        const float* __restrict__ pkey, float* __restrict__ keyball, float* __restrict__ keyy2) {
    __shared__ float red[4];
    const int p = blockIdx.x, tid = threadIdx.x;
    float v[3];
    float ss = 0.f;
    #pragma unroll
    for (int j = 0; j < 3; ++j) { v[j] = pkey[p * EMBED + tid + 256 * j]; ss += v[j] * v[j]; }
    ss = block_reduce_256(ss, red);
    const float scale1 = rsqrtf(fmaxf(ss, 1e-12f)) * 0.1f;   // l2_normalize * MAP_SCALE
    float su = 0.f;
    #pragma unroll
    for (int j = 0; j < 3; ++j) { v[j] *= scale1; su += v[j] * v[j]; }
    su = block_reduce_256(su, red);
    const float n = sqrtf(fmaxf(su, 1e-15f));
    const float f = tanhf(n) / n;                             // expmap0
    float sb = 0.f;
    #pragma unroll
    for (int j = 0; j < 3; ++j) { v[j] *= f; sb += v[j] * v[j]; }
    sb = block_reduce_256(sb, red);
    const float n2 = sqrtf(fmaxf(sb, 1e-15f));
    const float g = (n2 > MAX_NORM_F) ? (MAX_NORM_F / n2) : 1.0f;  // proju0
    #pragma unroll
    for (int j = 0; j < 3; ++j) keyball[p * EMBED + tid + 256 * j] = v[j] * g;
    if (tid == 0) keyy2[p] = sb * g * g;
}

// Fused per-batch tail: finalize mean, q_ball, distances, similarity, top-5, idx,
// reduce_sim, selected_key, prompt gather.  grid 128, block 256
__global__ __launch_bounds__(256) void topk_fused(
        const float* __restrict__ partial, const float* __restrict__ keyball,
        const float* __restrict__ keyy2, const float* __restrict__ prompt,
        float* __restrict__ out) {
    __shared__ float red[4];
    __shared__ float q[EMBED];
    __shared__ float xy[POOL];
    __shared__ float dist[POOL];
    __shared__ int sel_sh[TOPK];
    const int b = blockIdx.x, tid = threadIdx.x;

    // ---- finalize mean: sum NSLICE partials per column, /512 ----
    float v[3];
    {
        const float inv = 1.0f / (float)SEQ;
        #pragma unroll
        for (int j = 0; j < 3; ++j) {
            const int col = tid + 256 * j;
            float s = 0.f;
            #pragma unroll
            for (int sl = 0; sl < NSLICE; ++sl)
                s += partial[(long)(b * NSLICE + sl) * EMBED + col];
            v[j] = s * inv;
        }
    }

    // ---- q_ball = map_to_ball(x_mean[b]) ----
    float ss = 0.f;
    #pragma unroll
    for (int j = 0; j < 3; ++j) ss += v[j] * v[j];
    ss = block_reduce_256(ss, red);
    const float scale1 = rsqrtf(fmaxf(ss, 1e-12f)) * 0.1f;
    float su = 0.f;
    #pragma unroll
    for (int j = 0; j < 3; ++j) { v[j] *= scale1; su += v[j] * v[j]; }
    su = block_reduce_256(su, red);
    const float n = sqrtf(fmaxf(su, 1e-15f));
    const float f = tanhf(n) / n;
    float sb = 0.f;
    #pragma unroll
    for (int j = 0; j < 3; ++j) { v[j] *= f; sb += v[j] * v[j]; }
    sb = block_reduce_256(sb, red);
    const float n2 = sqrtf(fmaxf(sb, 1e-15f));
    const float g = (n2 > MAX_NORM_F) ? (MAX_NORM_F / n2) : 1.0f;
    const float x2 = sb * g * g;
    #pragma unroll
    for (int j = 0; j < 3; ++j) q[tid + 256 * j] = v[j] * g;
    __syncthreads();

    // ---- xy[p] = <q, key_ball[p]> : each wave handles 15 keys ----
    const int wave = tid >> 6, lane = tid & 63;
    for (int p = wave; p < POOL; p += 4) {
        const float* __restrict__ kb = keyball + p * EMBED;
        float acc = 0.f;
        #pragma unroll
        for (int d = 0; d < EMBED; d += 64) acc += q[d + lane] * kb[d + lane];
        #pragma unroll
        for (int m = 32; m >= 1; m >>= 1) acc += __shfl_xor(acc, m, 64);
        if (lane == 0) xy[p] = acc;
    }
    __syncthreads();

    // ---- distances (scalar-only mobius math) ----
    if (tid < POOL) {
        const float s = xy[tid];
        const float y2 = keyy2[tid];
        const float A = 1.0f - 2.0f * s + y2;       // coeff on -x in num
        const float B = 1.0f - x2;                  // coeff on  y in num
        const float num2 = A * A * x2 + B * B * y2 - 2.0f * A * B * s;
        const float den = fmaxf(1.0f - 2.0f * s + x2 * y2, 1e-15f);
        float nn = sqrtf(fmaxf(num2 / (den * den), 1e-15f));
        nn = fminf(fmaxf(nn, 0.0f), 1.0f - 1e-7f);
        const float dd = logf((1.0f + nn) / (1.0f - nn));   // 2*artanh(nn)
        dist[tid] = dd;
        out[OFF_SIM + (long)b * POOL + tid] = -dd;
    }
    __syncthreads();

    // ---- top-5 (largest similarity = smallest dist; ties -> lowest index), sort, reduce_sim ----
    if (tid == 0) {
        int sel[TOPK];
        unsigned long long mask = 0ULL;
        for (int k = 0; k < TOPK; ++k) {
            int best = 0; float bd = 1e30f;
            for (int p = 0; p < POOL; ++p) {
                if (mask & (1ULL << p)) continue;
                if (dist[p] < bd) { bd = dist[p]; best = p; }   // strict < keeps lowest index on tie
            }
            mask |= 1ULL << best;
            sel[k] = best;
        }
        #pragma unroll
        for (int i = 0; i < TOPK; ++i)
            for (int j2 = i + 1; j2 < TOPK; ++j2)
                if (sel[j2] < sel[i]) { int t = sel[i]; sel[i] = sel[j2]; sel[j2] = t; }
        float sum = 0.f;
        for (int k = 0; k < TOPK; ++k) {
            sum += dist[sel[k]];
            out[OFF_IDX + (long)b * TOPK + k] = (float)sel[k];
            sel_sh[k] = sel[k];
        }
        atomicAdd(&out[OFF_RS], sum * (1.0f / 128.0f));
    }
    __syncthreads();

    // ---- selected_key[b] = key_ball[idx] ----
    for (int t = tid; t < TOPK * EMBED; t += 256) {
        const int k = t / EMBED, d = t - k * EMBED;
        out[OFF_SK + (long)b * TOPK * EMBED + t] = keyball[sel_sh[k] * EMBED + d];
    }

    // ---- prompt gather -> output rows [0..24] (float4 granularity) ----
    {
        const float4* __restrict__ p4 = (const float4*)prompt;
        float4* __restrict__ o4 = (float4*)out;
        for (int t = tid; t < TOPK * LEN * EMBED4; t += 256) {
            const int r = t / EMBED4, c = t - r * EMBED4;
            const int k = r / LEN, l = r - k * LEN;
            const int pi = sel_sh[k];
            o4[((long)b * OUTROWS + r) * EMBED4 + c] = p4[((long)pi * LEN + l) * EMBED4 + c];
        }
    }
}

extern "C" void kernel_launch(void* const* d_in, const int* in_sizes, int n_in,
                              void* d_out, int out_size, void* d_ws, size_t ws_size,
                              hipStream_t stream) {
    const float* x      = (const float*)d_in[0];   // [128,512,768]
    const float* prompt = (const float*)d_in[1];   // [60,5,768]
    const float* pkey   = (const float*)d_in[2];   // [60,768]
    float* out = (float*)d_out;
    float* ws  = (float*)d_ws;

    float* partial = ws + WS_PARTIAL;
    float* keyball = ws + WS_KEYBALL;
    float* keyy2   = ws + WS_KEYY2;

    hipLaunchKernelGGL(mean_partial_copy, dim3(NSLICE, 128), dim3(192), 0, stream, x, out, partial);
    hipLaunchKernelGGL(keyball_kernel,    dim3(60),          dim3(256), 0, stream, pkey, keyball, keyy2);
    hipLaunchKernelGGL(topk_fused,        dim3(128),         dim3(256), 0, stream,
                       partial, keyball, keyy2, prompt, out);
}